// Round 2
// baseline (373.926 us; speedup 1.0000x reference)
//
#include <hip/hip_runtime.h>

// TreeLoss: hierarchical softmax-style loss over a fixed 2-level tree.
// States: 1 empty + 24 coarse-only + 1000 (coarse,fine) pairs.
// z = 1 + sum_c e_c + sum_{n>=24} e_{n%24} * e_n
// marginal(label<24=c)  = e_c * (1 + sum_{n≡c (24), n>=24} e_n)
// marginal(label>=24)   = e_{label%24} * e_label
// out = mean(log z - log marginal)
//
// R1: two-stage reduction replaced 8192 same-address atomics (−68 us).
// R2: label logic hoisted, 48-entry replicated LDS coarse table, vectorized.
// R3: 2 rows/wave, ds_read_b128 coefficient loads, table from registers,
//     conditional g-reduce. NEUTRAL -> issue work is hidden under the
//     134 MB stream; kernel is at its ~21 us BW floor.
// R4 (this round): the only structure left that isn't the stream:
//     - single kernel via last-block reduction (removes 2nd launch + gap +
//       1-block reduce exec). Counter zeroed per-iteration by a 4-byte
//       hipMemsetAsync (graph-safe, poison-safe). AGENT-scope atomics for
//       cross-XCD visibility (per-XCD L2s not coherent).
//     - nontemporal loads on the read-once fs stream (evict-first in L2).
//     If this is neutral too, the controllable portion is at the roofline.

constexpr int N_COARSE = 24;
constexpr int TOTAL = 1024;      // columns per row
constexpr int BATCH = 32768;
constexpr int WAVES_PER_BLOCK = 4;   // 256 threads
constexpr int ROWS_PER_WAVE = 2;
constexpr int ROWS_PER_BLOCK = WAVES_PER_BLOCK * ROWS_PER_WAVE;  // 8
constexpr int GRID1 = BATCH / ROWS_PER_BLOCK;                    // 4096

typedef float f32x4 __attribute__((ext_vector_type(4)));

__device__ __forceinline__ f32x4 ntload(const float* p) {
  return __builtin_nontemporal_load(reinterpret_cast<const f32x4*>(p));
}

__global__ __launch_bounds__(256) void treeloss_fused(
    const float* __restrict__ fs, const int* __restrict__ labels,
    float* __restrict__ partials, unsigned* __restrict__ counter,
    float* __restrict__ out) {
  const int wave = threadIdx.x >> 6;
  const int lane = threadIdx.x & 63;
  const int brow = blockIdx.x * ROWS_PER_BLOCK + wave * ROWS_PER_WAVE;

  // Coarse exp tables, one per (wave,row), replicated x2 so indices never
  // wrap: max index cbase+16+3 = 39 < 48. 16B-aligned rows (192 B stride).
  __shared__ __align__(16) float sc[WAVES_PER_BLOCK][ROWS_PER_WAVE][48];
  __shared__ float blocksum[WAVES_PER_BLOCK];
  __shared__ int lastFlag;

  const float* __restrict__ rowA = fs + (size_t)brow * TOTAL;
  const float* __restrict__ rowB = rowA + TOTAL;
  const int2 lab = *reinterpret_cast<const int2*>(labels + brow);  // brow even

  // All 8 row loads (2 rows x 4 float4/lane) in flight before any compute.
  // Nontemporal: fs is read exactly once; evict-first, no L2 alloc pressure.
  const f32x4 a0 = ntload(rowA + 4 * lane);
  const f32x4 a1 = ntload(rowA + 4 * lane + 256);
  const f32x4 a2 = ntload(rowA + 4 * lane + 512);
  const f32x4 a3 = ntload(rowA + 4 * lane + 768);
  const f32x4 c0 = ntload(rowB + 4 * lane);
  const f32x4 c1 = ntload(rowB + 4 * lane + 256);
  const f32x4 c2 = ntload(rowB + 4 * lane + 512);
  const f32x4 c3 = ntload(rowB + 4 * lane + 768);

  // Prefetch label logits (only consumed on lane 0 when label>=24).
  float fAl = 0.0f, fBl = 0.0f;
  if (lane == 0) { fAl = rowA[lab.x]; fBl = rowB[lab.y]; }

  // j=0 exps double as the coarse-table source: lanes 0..5 own n=0..23.
  const float eA0 = __expf(a0.x), eA1 = __expf(a0.y),
              eA2 = __expf(a0.z), eA3 = __expf(a0.w);
  const float eB0 = __expf(c0.x), eB1 = __expf(c0.y),
              eB2 = __expf(c0.z), eB3 = __expf(c0.w);
  if (lane < 6) {
    const int tb = lane * 4;  // 16B-aligned; +24 floats (96 B) also aligned
    const float4 vA = make_float4(eA0, eA1, eA2, eA3);
    const float4 vB = make_float4(eB0, eB1, eB2, eB3);
    *reinterpret_cast<float4*>(&sc[wave][0][tb]) = vA;
    *reinterpret_cast<float4*>(&sc[wave][0][tb + 24]) = vA;
    *reinterpret_cast<float4*>(&sc[wave][1][tb]) = vB;
    *reinterpret_cast<float4*>(&sc[wave][1][tb + 24]) = vB;
  }
  __syncthreads();

  // Coefficient float4s: cbase ∈ {0,4,..,20} floats -> 16B-aligned offsets;
  // +8/+16 floats keep alignment. K = (j*256)%24 ∈ {0,16,8,0} so j=3 reuses
  // the K=0 vector. Same-address lanes broadcast; 6 distinct cbase groups hit
  // disjoint bank sets -> conflict-free ds_read_b128.
  const int cbase = (lane * 4) % N_COARSE;
  const float* tA = sc[wave][0];
  const float* tB = sc[wave][1];
  const float4 csA0  = *reinterpret_cast<const float4*>(tA + cbase);
  const float4 csA16 = *reinterpret_cast<const float4*>(tA + cbase + 16);
  const float4 csA8  = *reinterpret_cast<const float4*>(tA + cbase + 8);
  const float4 csB0  = *reinterpret_cast<const float4*>(tB + cbase);
  const float4 csB16 = *reinterpret_cast<const float4*>(tB + cbase + 16);
  const float4 csB8  = *reinterpret_cast<const float4*>(tB + cbase + 8);

  float zpA, zpB;  // partial of (z - 1)
  if (lane < 6) {  // j=0, n<24: coarse-only states contribute e_n directly
    zpA = (eA0 + eA1) + (eA2 + eA3);
    zpB = (eB0 + eB1) + (eB2 + eB3);
  } else {         // j=0, n>=24: pair states, coefficient from table
    zpA = csA0.x * eA0 + csA0.y * eA1 + csA0.z * eA2 + csA0.w * eA3;
    zpB = csB0.x * eB0 + csB0.y * eB1 + csB0.z * eB2 + csB0.w * eB3;
  }
  // j=1 (K=16), j=2 (K=8), j=3 (K=0; reuses csX0)
  zpA += csA16.x * __expf(a1.x) + csA16.y * __expf(a1.y) +
         csA16.z * __expf(a1.z) + csA16.w * __expf(a1.w);
  zpA += csA8.x * __expf(a2.x) + csA8.y * __expf(a2.y) +
         csA8.z * __expf(a2.z) + csA8.w * __expf(a2.w);
  zpA += csA0.x * __expf(a3.x) + csA0.y * __expf(a3.y) +
         csA0.z * __expf(a3.z) + csA0.w * __expf(a3.w);
  zpB += csB16.x * __expf(c1.x) + csB16.y * __expf(c1.y) +
         csB16.z * __expf(c1.z) + csB16.w * __expf(c1.w);
  zpB += csB8.x * __expf(c2.x) + csB8.y * __expf(c2.y) +
         csB8.z * __expf(c2.z) + csB8.w * __expf(c2.w);
  zpB += csB0.x * __expf(c3.x) + csB0.y * __expf(c3.y) +
         csB0.z * __expf(c3.z) + csB0.w * __expf(c3.w);

  // Wave-wide butterfly reduce for zp (always needed).
#pragma unroll
  for (int off = 32; off > 0; off >>= 1) {
    zpA += __shfl_down(zpA, off);
    zpB += __shfl_down(zpB, off);
  }

  // Label gather + reduce only when label<24 (wave-uniform, ~2.3% of rows).
  // Fine nodes ≡ label (mod 24) are label+24*(lane+1), at most 42 of them.
  const bool needA = lab.x < N_COARSE;
  const bool needB = lab.y < N_COARSE;
  float gA = 0.0f, gB = 0.0f;
  if (needA) {
    const int idx = lab.x + N_COARSE * (lane + 1);
    if (idx < TOTAL) gA = __expf(rowA[idx]);
#pragma unroll
    for (int off = 32; off > 0; off >>= 1) gA += __shfl_down(gA, off);
  }
  if (needB) {
    const int idx = lab.y + N_COARSE * (lane + 1);
    if (idx < TOTAL) gB = __expf(rowB[idx]);
#pragma unroll
    for (int off = 32; off > 0; off >>= 1) gB += __shfl_down(gB, off);
  }

  if (lane == 0) {
    const float mA = needA ? tA[lab.x] * (1.0f + gA)
                           : tA[lab.x % N_COARSE] * __expf(fAl);
    const float mB = needB ? tB[lab.y] * (1.0f + gB)
                           : tB[lab.y % N_COARSE] * __expf(fBl);
    blocksum[wave] = (__logf(1.0f + zpA) - __logf(mA)) +
                     (__logf(1.0f + zpB) - __logf(mB));
  }
  __syncthreads();

  // Last-block reduction: publish partial (agent scope -> visible across
  // XCDs), bump the counter; the block that sees GRID1-1 finishes the job.
  if (threadIdx.x == 0) {
    const float bp =
        (blocksum[0] + blocksum[1]) + (blocksum[2] + blocksum[3]);
    __hip_atomic_store(&partials[blockIdx.x], bp, __ATOMIC_RELAXED,
                       __HIP_MEMORY_SCOPE_AGENT);
    const unsigned old = __hip_atomic_fetch_add(counter, 1u, __ATOMIC_ACQ_REL,
                                                __HIP_MEMORY_SCOPE_AGENT);
    lastFlag = (old == (unsigned)(GRID1 - 1));
  }
  __syncthreads();
  if (!lastFlag) return;

  // Final reduce: 256 threads x 16 coalesced agent loads each.
  const int tid = threadIdx.x;
  float s = 0.0f;
#pragma unroll
  for (int k = 0; k < GRID1 / 256; ++k)
    s += __hip_atomic_load(&partials[tid + 256 * k], __ATOMIC_RELAXED,
                           __HIP_MEMORY_SCOPE_AGENT);
#pragma unroll
  for (int off = 32; off > 0; off >>= 1) s += __shfl_down(s, off);
  if (lane == 0) blocksum[wave] = s;  // blocksum reusable: barrier above
  __syncthreads();
  if (tid == 0) {
    out[0] = ((blocksum[0] + blocksum[1]) + (blocksum[2] + blocksum[3])) *
             (1.0f / (float)BATCH);
  }
}

extern "C" void kernel_launch(void* const* d_in, const int* in_sizes, int n_in,
                              void* d_out, int out_size, void* d_ws, size_t ws_size,
                              hipStream_t stream) {
  const float* fs = (const float*)d_in[0];
  const int* labels = (const int*)d_in[1];
  // d_in[2] (stateSpace) is deterministic structure; hardcoded in the kernel.
  float* out = (float*)d_out;
  float* partials = (float*)d_ws;                        // 4096 floats
  unsigned* counter = (unsigned*)((char*)d_ws + GRID1 * sizeof(float));

  // Counter must be 0 each iteration (ws is poisoned between runs).
  hipMemsetAsync(counter, 0, sizeof(unsigned), stream);
  treeloss_fused<<<GRID1, 256, 0, stream>>>(fs, labels, partials, counter, out);
}

// Round 3
// 190.647 us; speedup vs baseline: 1.9614x; 1.9614x over previous
//
#include <hip/hip_runtime.h>

// TreeLoss: hierarchical softmax-style loss over a fixed 2-level tree.
// States: 1 empty + 24 coarse-only + 1000 (coarse,fine) pairs.
// z = 1 + sum_c e_c + sum_{n>=24} e_{n%24} * e_n
// marginal(label<24=c)  = e_c * (1 + sum_{n≡c (24), n>=24} e_n)
// marginal(label>=24)   = e_{label%24} * e_label
// out = mean(log z - log marginal)
//
// R1: two-stage reduction replaced 8192 same-address atomics (−68 us).
// R2: label logic hoisted, 48-entry replicated LDS coarse table, vectorized.
// R3: 2 rows/wave, ds_read_b128 coefficient loads, table from registers,
//     conditional g-reduce. NEUTRAL -> issue work is hidden under the
//     stream; kernel is at its BW floor (input is L3-resident, so the
//     floor is even below the 21 us HBM estimate).
// R4: FAILED (374 us). Last-block fusion via ACQ_REL agent atomics
//     serialized on cross-XCD release/acquire traffic (VALUBusy 3.7%,
//     kernel idle at 216 us); nontemporal loads defeated L3 residency
//     (FETCH_SIZE 0 -> 68 MB). Reverted.
// R5 (this round): exact revert to the R3-verified kernel. The remaining
//     ~140 us of dur_us is harness poison/restore (512 MiB fill = 78 us
//     tops every profile); controllable portion is at its floor.

constexpr int N_COARSE = 24;
constexpr int TOTAL = 1024;      // columns per row
constexpr int BATCH = 32768;
constexpr int WAVES_PER_BLOCK = 4;   // 256 threads
constexpr int ROWS_PER_WAVE = 2;
constexpr int ROWS_PER_BLOCK = WAVES_PER_BLOCK * ROWS_PER_WAVE;  // 8
constexpr int GRID1 = BATCH / ROWS_PER_BLOCK;                    // 4096

__global__ __launch_bounds__(256) void treeloss_partial(
    const float* __restrict__ fs, const int* __restrict__ labels,
    float* __restrict__ partials) {
  const int wave = threadIdx.x >> 6;
  const int lane = threadIdx.x & 63;
  const int brow = blockIdx.x * ROWS_PER_BLOCK + wave * ROWS_PER_WAVE;

  // Coarse exp tables, one per (wave,row), replicated x2 so indices never
  // wrap: max index cbase+16+3 = 39 < 48. 16B-aligned rows (192 B stride).
  __shared__ __align__(16) float sc[WAVES_PER_BLOCK][ROWS_PER_WAVE][48];
  __shared__ float blocksum[WAVES_PER_BLOCK];

  const float* __restrict__ rowA = fs + (size_t)brow * TOTAL;
  const float* __restrict__ rowB = rowA + TOTAL;
  const float4* __restrict__ rowA4 = reinterpret_cast<const float4*>(rowA);
  const float4* __restrict__ rowB4 = reinterpret_cast<const float4*>(rowB);
  const int2 lab = *reinterpret_cast<const int2*>(labels + brow);  // brow even

  // All 8 row loads (2 rows x 4 float4/lane) in flight before any compute.
  const float4 a0 = rowA4[lane];
  const float4 a1 = rowA4[lane + 64];
  const float4 a2 = rowA4[lane + 128];
  const float4 a3 = rowA4[lane + 192];
  const float4 c0 = rowB4[lane];
  const float4 c1 = rowB4[lane + 64];
  const float4 c2 = rowB4[lane + 128];
  const float4 c3 = rowB4[lane + 192];

  // Prefetch label logits (only consumed on lane 0 when label>=24).
  float fAl = 0.0f, fBl = 0.0f;
  if (lane == 0) { fAl = rowA[lab.x]; fBl = rowB[lab.y]; }

  // j=0 exps double as the coarse-table source: lanes 0..5 own n=0..23.
  const float eA0 = __expf(a0.x), eA1 = __expf(a0.y),
              eA2 = __expf(a0.z), eA3 = __expf(a0.w);
  const float eB0 = __expf(c0.x), eB1 = __expf(c0.y),
              eB2 = __expf(c0.z), eB3 = __expf(c0.w);
  if (lane < 6) {
    const int tb = lane * 4;  // 16B-aligned; +24 floats (96 B) also aligned
    const float4 vA = make_float4(eA0, eA1, eA2, eA3);
    const float4 vB = make_float4(eB0, eB1, eB2, eB3);
    *reinterpret_cast<float4*>(&sc[wave][0][tb]) = vA;
    *reinterpret_cast<float4*>(&sc[wave][0][tb + 24]) = vA;
    *reinterpret_cast<float4*>(&sc[wave][1][tb]) = vB;
    *reinterpret_cast<float4*>(&sc[wave][1][tb + 24]) = vB;
  }
  __syncthreads();

  // Coefficient float4s: cbase ∈ {0,4,..,20} floats -> byte offsets are
  // multiples of 16; +8/+16 floats keep alignment. K = (j*256)%24 ∈ {0,16,8,0}
  // so j=3 reuses the K=0 vector. Same-address lanes broadcast; the 6 distinct
  // cbase groups hit disjoint bank sets -> conflict-free.
  const int cbase = (lane * 4) % N_COARSE;
  const float* tA = sc[wave][0];
  const float* tB = sc[wave][1];
  const float4 csA0  = *reinterpret_cast<const float4*>(tA + cbase);
  const float4 csA16 = *reinterpret_cast<const float4*>(tA + cbase + 16);
  const float4 csA8  = *reinterpret_cast<const float4*>(tA + cbase + 8);
  const float4 csB0  = *reinterpret_cast<const float4*>(tB + cbase);
  const float4 csB16 = *reinterpret_cast<const float4*>(tB + cbase + 16);
  const float4 csB8  = *reinterpret_cast<const float4*>(tB + cbase + 8);

  float zpA, zpB;  // partial of (z - 1)
  if (lane < 6) {  // j=0, n<24: coarse-only states contribute e_n directly
    zpA = (eA0 + eA1) + (eA2 + eA3);
    zpB = (eB0 + eB1) + (eB2 + eB3);
  } else {         // j=0, n>=24: pair states, coefficient from table
    zpA = csA0.x * eA0 + csA0.y * eA1 + csA0.z * eA2 + csA0.w * eA3;
    zpB = csB0.x * eB0 + csB0.y * eB1 + csB0.z * eB2 + csB0.w * eB3;
  }
  // j=1 (K=16), j=2 (K=8), j=3 (K=0; reuses csX0)
  zpA += csA16.x * __expf(a1.x) + csA16.y * __expf(a1.y) +
         csA16.z * __expf(a1.z) + csA16.w * __expf(a1.w);
  zpA += csA8.x * __expf(a2.x) + csA8.y * __expf(a2.y) +
         csA8.z * __expf(a2.z) + csA8.w * __expf(a2.w);
  zpA += csA0.x * __expf(a3.x) + csA0.y * __expf(a3.y) +
         csA0.z * __expf(a3.z) + csA0.w * __expf(a3.w);
  zpB += csB16.x * __expf(c1.x) + csB16.y * __expf(c1.y) +
         csB16.z * __expf(c1.z) + csB16.w * __expf(c1.w);
  zpB += csB8.x * __expf(c2.x) + csB8.y * __expf(c2.y) +
         csB8.z * __expf(c2.z) + csB8.w * __expf(c2.w);
  zpB += csB0.x * __expf(c3.x) + csB0.y * __expf(c3.y) +
         csB0.z * __expf(c3.z) + csB0.w * __expf(c3.w);

  // Wave-wide butterfly reduce for zp (always needed).
#pragma unroll
  for (int off = 32; off > 0; off >>= 1) {
    zpA += __shfl_down(zpA, off);
    zpB += __shfl_down(zpB, off);
  }

  // Label gather + reduce only when label<24 (wave-uniform, ~2.3% of rows).
  // Fine nodes ≡ label (mod 24) are label+24*(lane+1), at most 42 of them.
  const bool needA = lab.x < N_COARSE;
  const bool needB = lab.y < N_COARSE;
  float gA = 0.0f, gB = 0.0f;
  if (needA) {
    const int idx = lab.x + N_COARSE * (lane + 1);
    if (idx < TOTAL) gA = __expf(rowA[idx]);
#pragma unroll
    for (int off = 32; off > 0; off >>= 1) gA += __shfl_down(gA, off);
  }
  if (needB) {
    const int idx = lab.y + N_COARSE * (lane + 1);
    if (idx < TOTAL) gB = __expf(rowB[idx]);
#pragma unroll
    for (int off = 32; off > 0; off >>= 1) gB += __shfl_down(gB, off);
  }

  if (lane == 0) {
    const float mA = needA ? tA[lab.x] * (1.0f + gA)
                           : tA[lab.x % N_COARSE] * __expf(fAl);
    const float mB = needB ? tB[lab.y] * (1.0f + gB)
                           : tB[lab.y % N_COARSE] * __expf(fBl);
    blocksum[wave] = (__logf(1.0f + zpA) - __logf(mA)) +
                     (__logf(1.0f + zpB) - __logf(mB));
  }
  __syncthreads();

  if (threadIdx.x == 0) {
    partials[blockIdx.x] =
        (blocksum[0] + blocksum[1]) + (blocksum[2] + blocksum[3]);
  }
}

__global__ __launch_bounds__(1024) void treeloss_reduce(
    const float* __restrict__ partials, float* __restrict__ out) {
  const int tid = threadIdx.x;
  const int lane = tid & 63;
  const int wave = tid >> 6;
  // 4096 partials = 1024 float4, exactly one per thread.
  const float4 a = reinterpret_cast<const float4*>(partials)[tid];
  float s = (a.x + a.y) + (a.z + a.w);
#pragma unroll
  for (int off = 32; off > 0; off >>= 1) s += __shfl_down(s, off);
  __shared__ float ps[16];
  if (lane == 0) ps[wave] = s;
  __syncthreads();
  if (tid == 0) {
    float t = 0.0f;
#pragma unroll
    for (int w = 0; w < 16; ++w) t += ps[w];
    out[0] = t * (1.0f / (float)BATCH);
  }
}

extern "C" void kernel_launch(void* const* d_in, const int* in_sizes, int n_in,
                              void* d_out, int out_size, void* d_ws, size_t ws_size,
                              hipStream_t stream) {
  const float* fs = (const float*)d_in[0];
  const int* labels = (const int*)d_in[1];
  // d_in[2] (stateSpace) is deterministic structure; hardcoded in the kernel.
  float* out = (float*)d_out;
  float* partials = (float*)d_ws;  // 4096 floats = 16 KiB scratch

  treeloss_partial<<<GRID1, 256, 0, stream>>>(fs, labels, partials);
  treeloss_reduce<<<1, 1024, 0, stream>>>(partials, out);
}